// Round 1
// baseline (8148.276 us; speedup 1.0000x reference)
//
#include <hip/hip_runtime.h>
#include <hip/hip_bf16.h>

#define BT 256
#define EPS 1e-5f

// ---------------------------------------------------------------------------
// Edge pass 0+1 fused: degree count + layer-1 (1-feature) aggregation
// ---------------------------------------------------------------------------
__global__ void k_count_agg1(const int* __restrict__ src, const int* __restrict__ dst,
                             const float* __restrict__ x,
                             float* __restrict__ cnt, float* __restrict__ agg1, int nE)
{
    int e = blockIdx.x * blockDim.x + threadIdx.x;
    if (e >= nE) return;
    int s = src[e];
    int d = dst[e];
    unsafeAtomicAdd(&cnt[d], 1.0f);
    unsafeAtomicAdd(&agg1[d], x[s]);
}

// cnt -> 1/max(cnt,1) in place
__global__ void k_inv(float* __restrict__ cnt, int n)
{
    int i = blockIdx.x * blockDim.x + threadIdx.x;
    if (i >= n) return;
    float c = cnt[i];
    cnt[i] = 1.0f / fmaxf(c, 1.0f);
}

// ---------------------------------------------------------------------------
// Layer 1 node transform: [N,1] -> [N,16], BN(eval) + ReLU fused
// ---------------------------------------------------------------------------
__global__ void k_l1(const float* __restrict__ agg1, const float* __restrict__ x,
                     const float* __restrict__ inv_cnt,
                     const float* __restrict__ W1l, const float* __restrict__ b1l,
                     const float* __restrict__ W1r,
                     const float* __restrict__ gam, const float* __restrict__ bet,
                     const float* __restrict__ mu,  const float* __restrict__ var,
                     float* __restrict__ hout, int n)
{
    __shared__ float sWl[16], sb[16], sWr[16], ssc[16], sbi[16];
    int t = threadIdx.x;
    if (t < 16) {
        sWl[t] = W1l[t]; sb[t] = b1l[t]; sWr[t] = W1r[t];
        float sc = gam[t] * rsqrtf(var[t] + EPS);
        ssc[t] = sc;
        sbi[t] = bet[t] - mu[t] * sc;
    }
    __syncthreads();
    int i = blockIdx.x * blockDim.x + t;
    if (i >= n) return;
    float m  = agg1[i] * inv_cnt[i];
    float xv = x[i];
    float o[16];
#pragma unroll
    for (int j = 0; j < 16; ++j) {
        float v = fmaf(m, sWl[j], sb[j]);
        v = fmaf(xv, sWr[j], v);
        o[j] = fmaxf(fmaf(v, ssc[j], sbi[j]), 0.0f);
    }
    float4* op = (float4*)(hout + (size_t)i * 16);
#pragma unroll
    for (int k = 0; k < 4; ++k)
        op[k] = make_float4(o[4*k], o[4*k+1], o[4*k+2], o[4*k+3]);
}

// ---------------------------------------------------------------------------
// 16-feature edge aggregation: agg[dst] += h[src]   (f32 HW atomics)
// ---------------------------------------------------------------------------
__global__ void k_agg16(const int* __restrict__ src, const int* __restrict__ dst,
                        const float* __restrict__ h, float* __restrict__ agg, int nE)
{
    int e = blockIdx.x * blockDim.x + threadIdx.x;
    if (e >= nE) return;
    int s = src[e];
    int d = dst[e];
    const float4* hp = (const float4*)(h + (size_t)s * 16);
    float* ap = agg + (size_t)d * 16;
#pragma unroll
    for (int k = 0; k < 4; ++k) {
        float4 v = hp[k];
        unsafeAtomicAdd(ap + 4*k + 0, v.x);
        unsafeAtomicAdd(ap + 4*k + 1, v.y);
        unsafeAtomicAdd(ap + 4*k + 2, v.z);
        unsafeAtomicAdd(ap + 4*k + 3, v.w);
    }
}

// ---------------------------------------------------------------------------
// 16->16 node transform + ReLU (layers 2,3). Weights staged in LDS.
// ---------------------------------------------------------------------------
__global__ void k_trans16(const float* __restrict__ agg, const float* __restrict__ h,
                          const float* __restrict__ inv_cnt,
                          const float* __restrict__ Wl, const float* __restrict__ bl,
                          const float* __restrict__ Wr,
                          float* __restrict__ hout, int n)
{
    __shared__ float sWl[256], sWr[256], sb[16];
    int t = threadIdx.x;
    if (t < 256) { sWl[t] = Wl[t]; sWr[t] = Wr[t]; }
    if (t < 16)  sb[t] = bl[t];
    __syncthreads();
    int i = blockIdx.x * blockDim.x + t;
    if (i >= n) return;
    float ic = inv_cnt[i];
    const float4* ap = (const float4*)(agg + (size_t)i * 16);
    const float4* hp = (const float4*)(h   + (size_t)i * 16);
    float a[16], xv[16];
#pragma unroll
    for (int k = 0; k < 4; ++k) {
        float4 av = ap[k], hv = hp[k];
        a[4*k+0] = av.x * ic; a[4*k+1] = av.y * ic;
        a[4*k+2] = av.z * ic; a[4*k+3] = av.w * ic;
        xv[4*k+0] = hv.x; xv[4*k+1] = hv.y; xv[4*k+2] = hv.z; xv[4*k+3] = hv.w;
    }
    float o[16];
#pragma unroll
    for (int j = 0; j < 16; ++j) {
        float acc = sb[j];
#pragma unroll
        for (int ii = 0; ii < 16; ++ii) acc = fmaf(a[ii],  sWl[j*16+ii], acc);
#pragma unroll
        for (int ii = 0; ii < 16; ++ii) acc = fmaf(xv[ii], sWr[j*16+ii], acc);
        o[j] = fmaxf(acc, 0.0f);
    }
    float4* op = (float4*)(hout + (size_t)i * 16);
#pragma unroll
    for (int k = 0; k < 4; ++k)
        op[k] = make_float4(o[4*k], o[4*k+1], o[4*k+2], o[4*k+3]);
}

// ---------------------------------------------------------------------------
// Layer 4 (16->32, no relu) + decoder MLP (32->32 relu, 32->2) + softmax
// ---------------------------------------------------------------------------
__global__ void k_final(const float* __restrict__ agg, const float* __restrict__ h,
                        const float* __restrict__ inv_cnt,
                        const float* __restrict__ W4l, const float* __restrict__ b4l,
                        const float* __restrict__ W4r,
                        const float* __restrict__ Wd1, const float* __restrict__ bd1,
                        const float* __restrict__ Wd2, const float* __restrict__ bd2,
                        float* __restrict__ out, int n)
{
    __shared__ float sW4l[512], sW4r[512], sb4[32];
    __shared__ float sWd1[1024], sbd1[32], sWd2[64], sbd2[2];
    int t = threadIdx.x;
    for (int k = t; k < 512;  k += blockDim.x) { sW4l[k] = W4l[k]; sW4r[k] = W4r[k]; }
    for (int k = t; k < 1024; k += blockDim.x) sWd1[k] = Wd1[k];
    if (t < 32) { sb4[t] = b4l[t]; sbd1[t] = bd1[t]; }
    if (t < 64) sWd2[t] = Wd2[t];
    if (t < 2)  sbd2[t] = bd2[t];
    __syncthreads();
    int i = blockIdx.x * blockDim.x + t;
    if (i >= n) return;
    float ic = inv_cnt[i];
    const float4* ap = (const float4*)(agg + (size_t)i * 16);
    const float4* hp = (const float4*)(h   + (size_t)i * 16);
    float a[16], xv[16];
#pragma unroll
    for (int k = 0; k < 4; ++k) {
        float4 av = ap[k], hv = hp[k];
        a[4*k+0] = av.x * ic; a[4*k+1] = av.y * ic;
        a[4*k+2] = av.z * ic; a[4*k+3] = av.w * ic;
        xv[4*k+0] = hv.x; xv[4*k+1] = hv.y; xv[4*k+2] = hv.z; xv[4*k+3] = hv.w;
    }
    float h4[32];
#pragma unroll
    for (int j = 0; j < 32; ++j) {
        float acc = sb4[j];
#pragma unroll
        for (int ii = 0; ii < 16; ++ii) acc = fmaf(a[ii],  sW4l[j*16+ii], acc);
#pragma unroll
        for (int ii = 0; ii < 16; ++ii) acc = fmaf(xv[ii], sW4r[j*16+ii], acc);
        h4[j] = acc;
    }
    float o0 = sbd2[0], o1 = sbd2[1];
#pragma unroll
    for (int k = 0; k < 32; ++k) {
        float z = sbd1[k];
#pragma unroll
        for (int j = 0; j < 32; ++j) z = fmaf(h4[j], sWd1[k*32+j], z);
        z = fmaxf(z, 0.0f);
        o0 = fmaf(z, sWd2[k],      o0);
        o1 = fmaf(z, sWd2[32 + k], o1);
    }
    float m  = fmaxf(o0, o1);
    float e0 = expf(o0 - m), e1 = expf(o1 - m);
    float inv = 1.0f / (e0 + e1);
    out[2*(size_t)i + 0] = e0 * inv;
    out[2*(size_t)i + 1] = e1 * inv;
}

// ---------------------------------------------------------------------------
extern "C" void kernel_launch(void* const* d_in, const int* in_sizes, int n_in,
                              void* d_out, int out_size, void* d_ws, size_t ws_size,
                              hipStream_t stream)
{
    const float* x   = (const float*)d_in[0];
    const int*   ei  = (const int*)d_in[1];
    const int    N   = in_sizes[0];          // 100000
    const int    E   = in_sizes[1] / 2;      // 3200000
    const int* src = ei;
    const int* dst = ei + E;

    const float* W1l = (const float*)d_in[2];
    const float* b1l = (const float*)d_in[3];
    const float* W1r = (const float*)d_in[4];
    const float* gam = (const float*)d_in[5];
    const float* bet = (const float*)d_in[6];
    const float* mu  = (const float*)d_in[7];
    const float* var = (const float*)d_in[8];
    const float* W2l = (const float*)d_in[9];
    const float* b2l = (const float*)d_in[10];
    const float* W2r = (const float*)d_in[11];
    const float* W3l = (const float*)d_in[12];
    const float* b3l = (const float*)d_in[13];
    const float* W3r = (const float*)d_in[14];
    const float* W4l = (const float*)d_in[15];
    const float* b4l = (const float*)d_in[16];
    const float* W4r = (const float*)d_in[17];
    const float* Wd1 = (const float*)d_in[18];
    const float* bd1 = (const float*)d_in[19];
    const float* Wd2 = (const float*)d_in[20];
    const float* bd2 = (const float*)d_in[21];

    float* ws      = (float*)d_ws;
    float* inv_cnt = ws;                         // N
    float* agg     = inv_cnt + N;                // N*16
    float* hA      = agg + (size_t)N * 16;       // N*16
    float* hB      = hA  + (size_t)N * 16;       // N*16

    int nbE = (E + BT - 1) / BT;
    int nbN = (N + BT - 1) / BT;

    // degree + layer-1 aggregation
    hipMemsetAsync(inv_cnt, 0, (size_t)N * sizeof(float), stream);
    hipMemsetAsync(agg,     0, (size_t)N * sizeof(float), stream);
    k_count_agg1<<<nbE, BT, 0, stream>>>(src, dst, x, inv_cnt, agg, E);
    k_inv<<<nbN, BT, 0, stream>>>(inv_cnt, N);
    k_l1<<<nbN, BT, 0, stream>>>(agg, x, inv_cnt, W1l, b1l, W1r, gam, bet, mu, var, hA, N);

    // layer 2: hA -> hB
    hipMemsetAsync(agg, 0, (size_t)N * 16 * sizeof(float), stream);
    k_agg16<<<nbE, BT, 0, stream>>>(src, dst, hA, agg, E);
    k_trans16<<<nbN, BT, 0, stream>>>(agg, hA, inv_cnt, W2l, b2l, W2r, hB, N);

    // layer 3: hB -> hA
    hipMemsetAsync(agg, 0, (size_t)N * 16 * sizeof(float), stream);
    k_agg16<<<nbE, BT, 0, stream>>>(src, dst, hB, agg, E);
    k_trans16<<<nbN, BT, 0, stream>>>(agg, hB, inv_cnt, W3l, b3l, W3r, hA, N);

    // layer 4 + decoder + softmax: hA -> out
    hipMemsetAsync(agg, 0, (size_t)N * 16 * sizeof(float), stream);
    k_agg16<<<nbE, BT, 0, stream>>>(src, dst, hA, agg, E);
    k_final<<<nbN, BT, 0, stream>>>(agg, hA, inv_cnt, W4l, b4l, W4r,
                                    Wd1, bd1, Wd2, bd2, (float*)d_out, N);
}

// Round 2
// 886.121 us; speedup vs baseline: 9.1954x; 9.1954x over previous
//
#include <hip/hip_runtime.h>
#include <hip/hip_bf16.h>

#define EPS 1e-5f

// ---------------------------------------------------------------------------
// CSR build pass 1: degree count (int atomics into rp[0..N))
// ---------------------------------------------------------------------------
__global__ void k_count(const int* __restrict__ dst, int* __restrict__ rp, int nE)
{
    int e = blockIdx.x * blockDim.x + threadIdx.x;
    if (e >= nE) return;
    atomicAdd(&rp[dst[e]], 1);
}

// ---------------------------------------------------------------------------
// CSR build pass 2: single-block exclusive scan (in place on rp),
// also emits cursor copy and inv_cnt.
// ---------------------------------------------------------------------------
__global__ void k_scan(int* __restrict__ rp, int* __restrict__ cursor,
                       float* __restrict__ inv_cnt, int n, int nE)
{
    __shared__ int ls[1024];
    int t = threadIdx.x;
    int C = (n + 1023) >> 10;
    int lo = t * C;
    int hi = lo + C; if (hi > n) hi = n; if (lo > n) lo = n;
    int s = 0;
    for (int k = lo; k < hi; ++k) s += rp[k];
    ls[t] = s;
    __syncthreads();
    for (int off = 1; off < 1024; off <<= 1) {
        int v = (t >= off) ? ls[t - off] : 0;
        __syncthreads();
        ls[t] += v;
        __syncthreads();
    }
    int run = (t == 0) ? 0 : ls[t - 1];
    for (int k = lo; k < hi; ++k) {
        int c = rp[k];
        rp[k] = run;
        cursor[k] = run;
        inv_cnt[k] = 1.0f / fmaxf((float)c, 1.0f);
        run += c;
    }
    if (t == 1023) rp[n] = nE;
}

// ---------------------------------------------------------------------------
// CSR build pass 3: scatter src ids into neighbor lists
// ---------------------------------------------------------------------------
__global__ void k_scatter(const int* __restrict__ src, const int* __restrict__ dst,
                          int* __restrict__ cursor, int* __restrict__ csr, int nE)
{
    int e = blockIdx.x * blockDim.x + threadIdx.x;
    if (e >= nE) return;
    int d = dst[e];
    int pos = atomicAdd(&cursor[d], 1);
    csr[pos] = src[e];
}

// ---------------------------------------------------------------------------
// Layer 1: gather mean of x (1 feature) + 1->16 transform + BN + ReLU
// one thread per node
// ---------------------------------------------------------------------------
__global__ void k_l1g(const int* __restrict__ rp, const int* __restrict__ csr,
                      const float* __restrict__ inv_cnt, const float* __restrict__ x,
                      const float* __restrict__ W1l, const float* __restrict__ b1l,
                      const float* __restrict__ W1r,
                      const float* __restrict__ gam, const float* __restrict__ bet,
                      const float* __restrict__ mu,  const float* __restrict__ var,
                      float* __restrict__ hout, int n)
{
    __shared__ float sWl[16], sb[16], sWr[16], ssc[16], sbi[16];
    int t = threadIdx.x;
    if (t < 16) {
        sWl[t] = W1l[t]; sb[t] = b1l[t]; sWr[t] = W1r[t];
        float sc = gam[t] * rsqrtf(var[t] + EPS);
        ssc[t] = sc;
        sbi[t] = bet[t] - mu[t] * sc;
    }
    __syncthreads();
    int i = blockIdx.x * blockDim.x + t;
    if (i >= n) return;
    int r0 = rp[i], r1 = rp[i + 1];
    float acc = 0.0f;
#pragma unroll 4
    for (int k = r0; k < r1; ++k) acc += x[csr[k]];
    float m  = acc * inv_cnt[i];
    float xv = x[i];
    float o[16];
#pragma unroll
    for (int j = 0; j < 16; ++j) {
        float v = fmaf(m, sWl[j], sb[j]);
        v = fmaf(xv, sWr[j], v);
        o[j] = fmaxf(fmaf(v, ssc[j], sbi[j]), 0.0f);
    }
    float4* op = (float4*)(hout + (size_t)i * 16);
#pragma unroll
    for (int k = 0; k < 4; ++k)
        op[k] = make_float4(o[4*k], o[4*k+1], o[4*k+2], o[4*k+3]);
}

// ---------------------------------------------------------------------------
// Layers 2,3: fused gather-mean (16 feats) + 16->16 transform + ReLU.
// 16 threads per node (thread f owns feature f); 16 nodes per 256-block.
// ---------------------------------------------------------------------------
__global__ void k_sage16(const int* __restrict__ rp, const int* __restrict__ csr,
                         const float* __restrict__ inv_cnt, const float* __restrict__ h,
                         const float* __restrict__ Wl, const float* __restrict__ bl,
                         const float* __restrict__ Wr,
                         float* __restrict__ hout, int n)
{
    __shared__ float sWlT[256], sWrT[256], sb[16];
    __shared__ float sA[16][17], sX[16][17];
    int t = threadIdx.x;
    {   // load weights transposed: sWT[ii*16+j] = W[j*16+ii]
        int j = t & 15, ii = t >> 4;
        sWlT[ii * 16 + j] = Wl[j * 16 + ii];
        sWrT[ii * 16 + j] = Wr[j * 16 + ii];
    }
    if (t < 16) sb[t] = bl[t];
    int grp = t >> 4, f = t & 15;
    int i = blockIdx.x * 16 + grp;
    bool valid = i < n;
    float acc = 0.0f, ic = 0.0f, hs = 0.0f;
    if (valid) {
        int r0 = rp[i], r1 = rp[i + 1];
#pragma unroll 4
        for (int k = r0; k < r1; ++k) {
            int nb = csr[k];                       // same addr for 16 lanes: HW broadcast
            acc += h[(size_t)nb * 16 + f];         // 64B coalesced per neighbor
        }
        ic = inv_cnt[i];
        hs = h[(size_t)i * 16 + f];
    }
    sA[grp][f] = acc * ic;
    sX[grp][f] = hs;
    __syncthreads();
    if (valid) {
        float o = sb[f];
#pragma unroll
        for (int ii = 0; ii < 16; ++ii) {
            o = fmaf(sA[grp][ii], sWlT[ii * 16 + f], o);
            o = fmaf(sX[grp][ii], sWrT[ii * 16 + f], o);
        }
        hout[(size_t)i * 16 + f] = fmaxf(o, 0.0f);
    }
}

// ---------------------------------------------------------------------------
// Layer 4 + decoder + softmax, fused with gather. 16 threads per node.
// ---------------------------------------------------------------------------
__global__ void k_fin(const int* __restrict__ rp, const int* __restrict__ csr,
                      const float* __restrict__ inv_cnt, const float* __restrict__ h,
                      const float* __restrict__ W4l, const float* __restrict__ b4l,
                      const float* __restrict__ W4r,
                      const float* __restrict__ Wd1, const float* __restrict__ bd1,
                      const float* __restrict__ Wd2, const float* __restrict__ bd2,
                      float* __restrict__ out, int n)
{
    __shared__ float sW4lT[512], sW4rT[512], sb4[32];
    __shared__ float sWd1T[1024], sbd1[32], sWd2[64], sbd2[2];
    __shared__ float sA[16][17], sX[16][17], sH4[16][33];
    int t = threadIdx.x;
    for (int k = t; k < 512; k += 256) {      // W4{l,r}: [32][16] -> T[ii*32+j]
        int j = k >> 4, ii = k & 15;
        sW4lT[ii * 32 + j] = W4l[k];
        sW4rT[ii * 32 + j] = W4r[k];
    }
    for (int k = t; k < 1024; k += 256) {     // Wd1: [32][32] -> T[k32*32+j]
        int j = k >> 5, ii = k & 31;
        sWd1T[ii * 32 + j] = Wd1[k];
    }
    if (t < 32) { sb4[t] = b4l[t]; sbd1[t] = bd1[t]; }
    if (t < 64) sWd2[t] = Wd2[t];
    if (t < 2)  sbd2[t] = bd2[t];
    int grp = t >> 4, f = t & 15;
    int i = blockIdx.x * 16 + grp;
    bool valid = i < n;
    float acc = 0.0f, ic = 0.0f, hs = 0.0f;
    if (valid) {
        int r0 = rp[i], r1 = rp[i + 1];
#pragma unroll 4
        for (int k = r0; k < r1; ++k) acc += h[(size_t)csr[k] * 16 + f];
        ic = inv_cnt[i];
        hs = h[(size_t)i * 16 + f];
    }
    sA[grp][f] = acc * ic;
    sX[grp][f] = hs;
    __syncthreads();
    // h4[j] for j=f and j=f+16
    float h4a = sb4[f], h4b = sb4[f + 16];
#pragma unroll
    for (int ii = 0; ii < 16; ++ii) {
        float a  = sA[grp][ii];
        float xx = sX[grp][ii];
        h4a = fmaf(a,  sW4lT[ii * 32 + f],      h4a);
        h4b = fmaf(a,  sW4lT[ii * 32 + f + 16], h4b);
        h4a = fmaf(xx, sW4rT[ii * 32 + f],      h4a);
        h4b = fmaf(xx, sW4rT[ii * 32 + f + 16], h4b);
    }
    sH4[grp][f] = h4a;
    sH4[grp][f + 16] = h4b;
    __syncthreads();
    // decoder layer 1 (relu) + partial of output dots
    float za = sbd1[f], zb = sbd1[f + 16];
#pragma unroll
    for (int k = 0; k < 32; ++k) {
        float hv = sH4[grp][k];
        za = fmaf(hv, sWd1T[k * 32 + f],      za);
        zb = fmaf(hv, sWd1T[k * 32 + f + 16], zb);
    }
    za = fmaxf(za, 0.0f);
    zb = fmaxf(zb, 0.0f);
    float o0 = za * sWd2[f]      + zb * sWd2[f + 16];
    float o1 = za * sWd2[32 + f] + zb * sWd2[32 + f + 16];
    // reduce over the 16-lane group (lanes are contiguous, masks stay in-group)
#pragma unroll
    for (int m = 8; m >= 1; m >>= 1) {
        o0 += __shfl_xor(o0, m, 64);
        o1 += __shfl_xor(o1, m, 64);
    }
    if (valid && f == 0) {
        o0 += sbd2[0]; o1 += sbd2[1];
        float mx = fmaxf(o0, o1);
        float e0 = expf(o0 - mx), e1 = expf(o1 - mx);
        float inv = 1.0f / (e0 + e1);
        out[(size_t)2 * i + 0] = e0 * inv;
        out[(size_t)2 * i + 1] = e1 * inv;
    }
}

// ---------------------------------------------------------------------------
extern "C" void kernel_launch(void* const* d_in, const int* in_sizes, int n_in,
                              void* d_out, int out_size, void* d_ws, size_t ws_size,
                              hipStream_t stream)
{
    const float* x  = (const float*)d_in[0];
    const int*   ei = (const int*)d_in[1];
    const int    N  = in_sizes[0];
    const int    E  = in_sizes[1] / 2;
    const int* src = ei;
    const int* dst = ei + E;

    const float* W1l = (const float*)d_in[2];
    const float* b1l = (const float*)d_in[3];
    const float* W1r = (const float*)d_in[4];
    const float* gam = (const float*)d_in[5];
    const float* bet = (const float*)d_in[6];
    const float* mu  = (const float*)d_in[7];
    const float* var = (const float*)d_in[8];
    const float* W2l = (const float*)d_in[9];
    const float* b2l = (const float*)d_in[10];
    const float* W2r = (const float*)d_in[11];
    const float* W3l = (const float*)d_in[12];
    const float* b3l = (const float*)d_in[13];
    const float* W3r = (const float*)d_in[14];
    const float* W4l = (const float*)d_in[15];
    const float* b4l = (const float*)d_in[16];
    const float* W4r = (const float*)d_in[17];
    const float* Wd1 = (const float*)d_in[18];
    const float* bd1 = (const float*)d_in[19];
    const float* Wd2 = (const float*)d_in[20];
    const float* bd2 = (const float*)d_in[21];

    // workspace layout (all 4B elems, 16B-aligned blocks)
    char*  base = (char*)d_ws;
    size_t off  = 0;
    auto alloc = [&](size_t elems) { size_t p = off; off += ((elems + 3) & ~(size_t)3) * 4; return p; };
    float* inv_cnt = (float*)(base + alloc(N));
    int*   rp      = (int*)  (base + alloc(N + 1));
    int*   csr     = (int*)  (base + alloc(E));
    float* hA      = (float*)(base + alloc((size_t)N * 16));
    float* hB      = (float*)(base + alloc((size_t)N * 16));
    int*   cursor  = (int*)hB;   // alias: cursor dead before hB's first write

    int nbE  = (E + 255) / 256;
    int nbN  = (N + 255) / 256;
    int nbN16 = (N + 15) / 16;

    // --- build CSR ---
    hipMemsetAsync(rp, 0, (size_t)(N + 1) * sizeof(int), stream);
    k_count<<<nbE, 256, 0, stream>>>(dst, rp, E);
    k_scan<<<1, 1024, 0, stream>>>(rp, cursor, inv_cnt, N, E);
    k_scatter<<<nbE, 256, 0, stream>>>(src, dst, cursor, csr, E);

    // --- layers ---
    k_l1g<<<nbN, 256, 0, stream>>>(rp, csr, inv_cnt, x, W1l, b1l, W1r,
                                   gam, bet, mu, var, hA, N);
    k_sage16<<<nbN16, 256, 0, stream>>>(rp, csr, inv_cnt, hA, W2l, b2l, W2r, hB, N);
    k_sage16<<<nbN16, 256, 0, stream>>>(rp, csr, inv_cnt, hB, W3l, b3l, W3r, hA, N);
    k_fin<<<nbN16, 256, 0, stream>>>(rp, csr, inv_cnt, hA, W4l, b4l, W4r,
                                     Wd1, bd1, Wd2, bd2, (float*)d_out, N);
}

// Round 3
// 710.358 us; speedup vs baseline: 11.4707x; 1.2474x over previous
//
#include <hip/hip_runtime.h>
#include <hip/hip_bf16.h>

#define EPS 1e-5f
typedef __hip_bfloat16 bf16;

// ---------------------------------------------------------------------------
// XCD-sliced degree count: blocks with bid&7==s only count dst in slice s.
// Edge list re-reads are L3-served; rp slice (50KB) stays hot in local L2.
// ---------------------------------------------------------------------------
__global__ void k_count(const int* __restrict__ dst, int* __restrict__ rp,
                        int n, int nE)
{
    int slice = blockIdx.x & 7;
    int lo = (int)(((long long)slice * n) >> 3);
    int hi = (int)(((long long)(slice + 1) * n) >> 3);
    int tid = (blockIdx.x >> 3) * blockDim.x + threadIdx.x;
    int stride = (gridDim.x >> 3) * blockDim.x;
    for (int e = tid; e < nE; e += stride) {
        int d = dst[e];
        if (d >= lo && d < hi) atomicAdd(&rp[d], 1);
    }
}

// ---------------------------------------------------------------------------
// Single-block exclusive scan over rp; emits cursor copy + inv_cnt.
// ---------------------------------------------------------------------------
__global__ void k_scan(int* __restrict__ rp, int* __restrict__ cursor,
                       float* __restrict__ inv_cnt, int n, int nE)
{
    __shared__ int ls[1024];
    int t = threadIdx.x;
    int C = (n + 1023) >> 10;
    int lo = t * C;
    int hi = lo + C; if (hi > n) hi = n; if (lo > n) lo = n;
    int s = 0;
    for (int k = lo; k < hi; ++k) s += rp[k];
    ls[t] = s;
    __syncthreads();
    for (int off = 1; off < 1024; off <<= 1) {
        int v = (t >= off) ? ls[t - off] : 0;
        __syncthreads();
        ls[t] += v;
        __syncthreads();
    }
    int run = (t == 0) ? 0 : ls[t - 1];
    for (int k = lo; k < hi; ++k) {
        int c = rp[k];
        rp[k] = run;
        cursor[k] = run;
        inv_cnt[k] = 1.0f / fmaxf((float)c, 1.0f);
        run += c;
    }
    if (t == 1023) rp[n] = nE;
}

// ---------------------------------------------------------------------------
// XCD-sliced scatter: each slice's csr region (~1.6MB) dirty only in one L2.
// ---------------------------------------------------------------------------
__global__ void k_scatter(const int* __restrict__ src, const int* __restrict__ dst,
                          int* __restrict__ cursor, int* __restrict__ csr,
                          int n, int nE)
{
    int slice = blockIdx.x & 7;
    int lo = (int)(((long long)slice * n) >> 3);
    int hi = (int)(((long long)(slice + 1) * n) >> 3);
    int tid = (blockIdx.x >> 3) * blockDim.x + threadIdx.x;
    int stride = (gridDim.x >> 3) * blockDim.x;
    for (int e = tid; e < nE; e += stride) {
        int d = dst[e];
        if (d >= lo && d < hi) {
            int pos = atomicAdd(&cursor[d], 1);
            csr[pos] = src[e];
        }
    }
}

// ---------------------------------------------------------------------------
// Layer 1: 16 lanes per node; lane f strides neighbors (coalesced csr reads),
// shfl-reduce, then lane f computes feature f. BN+ReLU fused. bf16 out.
// ---------------------------------------------------------------------------
__global__ void k_l1g(const int* __restrict__ rp, const int* __restrict__ csr,
                      const float* __restrict__ inv_cnt, const float* __restrict__ x,
                      const float* __restrict__ W1l, const float* __restrict__ b1l,
                      const float* __restrict__ W1r,
                      const float* __restrict__ gam, const float* __restrict__ bet,
                      const float* __restrict__ mu,  const float* __restrict__ var,
                      bf16* __restrict__ hout, int n)
{
    __shared__ float sWl[16], sb[16], sWr[16], ssc[16], sbi[16];
    int t = threadIdx.x;
    if (t < 16) {
        sWl[t] = W1l[t]; sb[t] = b1l[t]; sWr[t] = W1r[t];
        float sc = gam[t] * rsqrtf(var[t] + EPS);
        ssc[t] = sc;
        sbi[t] = bet[t] - mu[t] * sc;
    }
    __syncthreads();
    int grp = t >> 4, f = t & 15;
    int i = blockIdx.x * 16 + grp;
    if (i >= n) return;
    int r0 = rp[i], r1 = rp[i + 1];
    float s = 0.0f;
    for (int k = r0 + f; k < r1; k += 16) s += x[csr[k]];
#pragma unroll
    for (int m = 8; m >= 1; m >>= 1) s += __shfl_xor(s, m, 64);
    float mean = s * inv_cnt[i];
    float xv = x[i];
    float v = fmaf(mean, sWl[f], sb[f]);
    v = fmaf(xv, sWr[f], v);
    v = fmaxf(fmaf(v, ssc[f], sbi[f]), 0.0f);
    hout[(size_t)i * 16 + f] = __float2bfloat16(v);
}

// ---------------------------------------------------------------------------
// Layers 2,3: fused gather-mean (16 bf16 feats) + 16->16 transform + ReLU.
// 16 threads per node (lane f owns feature f). h is 3.2MB bf16 -> L2-resident.
// ---------------------------------------------------------------------------
__global__ void k_sage16(const int* __restrict__ rp, const int* __restrict__ csr,
                         const float* __restrict__ inv_cnt, const bf16* __restrict__ h,
                         const float* __restrict__ Wl, const float* __restrict__ bl,
                         const float* __restrict__ Wr,
                         bf16* __restrict__ hout, int n)
{
    __shared__ float sWlT[256], sWrT[256], sb[16];
    __shared__ float sA[16][17], sX[16][17];
    int t = threadIdx.x;
    {   // load weights transposed: sWT[ii*16+j] = W[j*16+ii]
        int j = t & 15, ii = t >> 4;
        sWlT[ii * 16 + j] = Wl[j * 16 + ii];
        sWrT[ii * 16 + j] = Wr[j * 16 + ii];
    }
    if (t < 16) sb[t] = bl[t];
    int grp = t >> 4, f = t & 15;
    int i = blockIdx.x * 16 + grp;
    bool valid = i < n;
    float acc = 0.0f, ic = 0.0f, hs = 0.0f;
    if (valid) {
        int r0 = rp[i], r1 = rp[i + 1];
#pragma unroll 4
        for (int k = r0; k < r1; ++k) {
            int nb = csr[k];                            // broadcast load
            acc += __bfloat162float(h[(size_t)nb * 16 + f]);  // 32B/neighbor
        }
        ic = inv_cnt[i];
        hs = __bfloat162float(h[(size_t)i * 16 + f]);
    }
    sA[grp][f] = acc * ic;
    sX[grp][f] = hs;
    __syncthreads();
    if (valid) {
        float o = sb[f];
#pragma unroll
        for (int ii = 0; ii < 16; ++ii) {
            o = fmaf(sA[grp][ii], sWlT[ii * 16 + f], o);
            o = fmaf(sX[grp][ii], sWrT[ii * 16 + f], o);
        }
        hout[(size_t)i * 16 + f] = __float2bfloat16(fmaxf(o, 0.0f));
    }
}

// ---------------------------------------------------------------------------
// Layer 4 + decoder + softmax, fused with gather. 16 threads per node.
// ---------------------------------------------------------------------------
__global__ void k_fin(const int* __restrict__ rp, const int* __restrict__ csr,
                      const float* __restrict__ inv_cnt, const bf16* __restrict__ h,
                      const float* __restrict__ W4l, const float* __restrict__ b4l,
                      const float* __restrict__ W4r,
                      const float* __restrict__ Wd1, const float* __restrict__ bd1,
                      const float* __restrict__ Wd2, const float* __restrict__ bd2,
                      float* __restrict__ out, int n)
{
    __shared__ float sW4lT[512], sW4rT[512], sb4[32];
    __shared__ float sWd1T[1024], sbd1[32], sWd2[64], sbd2[2];
    __shared__ float sA[16][17], sX[16][17], sH4[16][33];
    int t = threadIdx.x;
    for (int k = t; k < 512; k += 256) {      // W4{l,r}: [32][16] -> T[ii*32+j]
        int j = k >> 4, ii = k & 15;
        sW4lT[ii * 32 + j] = W4l[k];
        sW4rT[ii * 32 + j] = W4r[k];
    }
    for (int k = t; k < 1024; k += 256) {     // Wd1: [32][32] -> T[ii*32+j]
        int j = k >> 5, ii = k & 31;
        sWd1T[ii * 32 + j] = Wd1[k];
    }
    if (t < 32) { sb4[t] = b4l[t]; sbd1[t] = bd1[t]; }
    if (t < 64) sWd2[t] = Wd2[t];
    if (t < 2)  sbd2[t] = bd2[t];
    int grp = t >> 4, f = t & 15;
    int i = blockIdx.x * 16 + grp;
    bool valid = i < n;
    float acc = 0.0f, ic = 0.0f, hs = 0.0f;
    if (valid) {
        int r0 = rp[i], r1 = rp[i + 1];
#pragma unroll 4
        for (int k = r0; k < r1; ++k) acc += __bfloat162float(h[(size_t)csr[k] * 16 + f]);
        ic = inv_cnt[i];
        hs = __bfloat162float(h[(size_t)i * 16 + f]);
    }
    sA[grp][f] = acc * ic;
    sX[grp][f] = hs;
    __syncthreads();
    float h4a = sb4[f], h4b = sb4[f + 16];
#pragma unroll
    for (int ii = 0; ii < 16; ++ii) {
        float a  = sA[grp][ii];
        float xx = sX[grp][ii];
        h4a = fmaf(a,  sW4lT[ii * 32 + f],      h4a);
        h4b = fmaf(a,  sW4lT[ii * 32 + f + 16], h4b);
        h4a = fmaf(xx, sW4rT[ii * 32 + f],      h4a);
        h4b = fmaf(xx, sW4rT[ii * 32 + f + 16], h4b);
    }
    sH4[grp][f] = h4a;
    sH4[grp][f + 16] = h4b;
    __syncthreads();
    float za = sbd1[f], zb = sbd1[f + 16];
#pragma unroll
    for (int k = 0; k < 32; ++k) {
        float hv = sH4[grp][k];
        za = fmaf(hv, sWd1T[k * 32 + f],      za);
        zb = fmaf(hv, sWd1T[k * 32 + f + 16], zb);
    }
    za = fmaxf(za, 0.0f);
    zb = fmaxf(zb, 0.0f);
    float o0 = za * sWd2[f]      + zb * sWd2[f + 16];
    float o1 = za * sWd2[32 + f] + zb * sWd2[32 + f + 16];
#pragma unroll
    for (int m = 8; m >= 1; m >>= 1) {
        o0 += __shfl_xor(o0, m, 64);
        o1 += __shfl_xor(o1, m, 64);
    }
    if (valid && f == 0) {
        o0 += sbd2[0]; o1 += sbd2[1];
        float mx = fmaxf(o0, o1);
        float e0 = expf(o0 - mx), e1 = expf(o1 - mx);
        float inv = 1.0f / (e0 + e1);
        out[(size_t)2 * i + 0] = e0 * inv;
        out[(size_t)2 * i + 1] = e1 * inv;
    }
}

// ---------------------------------------------------------------------------
extern "C" void kernel_launch(void* const* d_in, const int* in_sizes, int n_in,
                              void* d_out, int out_size, void* d_ws, size_t ws_size,
                              hipStream_t stream)
{
    const float* x  = (const float*)d_in[0];
    const int*   ei = (const int*)d_in[1];
    const int    N  = in_sizes[0];
    const int    E  = in_sizes[1] / 2;
    const int* src = ei;
    const int* dst = ei + E;

    const float* W1l = (const float*)d_in[2];
    const float* b1l = (const float*)d_in[3];
    const float* W1r = (const float*)d_in[4];
    const float* gam = (const float*)d_in[5];
    const float* bet = (const float*)d_in[6];
    const float* mu  = (const float*)d_in[7];
    const float* var = (const float*)d_in[8];
    const float* W2l = (const float*)d_in[9];
    const float* b2l = (const float*)d_in[10];
    const float* W2r = (const float*)d_in[11];
    const float* W3l = (const float*)d_in[12];
    const float* b3l = (const float*)d_in[13];
    const float* W3r = (const float*)d_in[14];
    const float* W4l = (const float*)d_in[15];
    const float* b4l = (const float*)d_in[16];
    const float* W4r = (const float*)d_in[17];
    const float* Wd1 = (const float*)d_in[18];
    const float* bd1 = (const float*)d_in[19];
    const float* Wd2 = (const float*)d_in[20];
    const float* bd2 = (const float*)d_in[21];

    char*  base = (char*)d_ws;
    size_t off  = 0;
    auto alloc = [&](size_t bytes) { size_t p = off; off += (bytes + 15) & ~(size_t)15; return p; };
    float* inv_cnt = (float*)(base + alloc((size_t)N * 4));
    int*   rp      = (int*)  (base + alloc((size_t)(N + 1) * 4));
    int*   cursor  = (int*)  (base + alloc((size_t)N * 4));
    int*   csr     = (int*)  (base + alloc((size_t)E * 4));
    bf16*  hA      = (bf16*) (base + alloc((size_t)N * 16 * 2));
    bf16*  hB      = (bf16*) (base + alloc((size_t)N * 16 * 2));

    int nbN16 = (N + 15) / 16;
    int nbEdge = 8 * 256;        // 8 XCD slices x 256 chunks

    // --- build CSR (XCD-sliced atomics) ---
    hipMemsetAsync(rp, 0, (size_t)(N + 1) * sizeof(int), stream);
    k_count<<<nbEdge, 256, 0, stream>>>(dst, rp, N, E);
    k_scan<<<1, 1024, 0, stream>>>(rp, cursor, inv_cnt, N, E);
    k_scatter<<<nbEdge, 256, 0, stream>>>(src, dst, cursor, csr, N, E);

    // --- layers ---
    k_l1g<<<nbN16, 256, 0, stream>>>(rp, csr, inv_cnt, x, W1l, b1l, W1r,
                                     gam, bet, mu, var, hA, N);
    k_sage16<<<nbN16, 256, 0, stream>>>(rp, csr, inv_cnt, hA, W2l, b2l, W2r, hB, N);
    k_sage16<<<nbN16, 256, 0, stream>>>(rp, csr, inv_cnt, hB, W3l, b3l, W3r, hA, N);
    k_fin<<<nbN16, 256, 0, stream>>>(rp, csr, inv_cnt, hA, W4l, b4l, W4r,
                                     Wd1, bd1, Wd2, bd2, (float*)d_out, N);
}

// Round 4
// 445.188 us; speedup vs baseline: 18.3030x; 1.5956x over previous
//
#include <hip/hip_runtime.h>
#include <hip/hip_bf16.h>

#define EPS 1e-5f
#define SCH 512          // scan chunk = 256 threads x 2 elems
typedef __hip_bfloat16 bf16;

// ---------------------------------------------------------------------------
// XCD-sliced degree count: blocks with bid&7==s only count dst in slice s.
// ---------------------------------------------------------------------------
__global__ void k_count(const int* __restrict__ dst, int* __restrict__ rp,
                        int n, int nE)
{
    int slice = blockIdx.x & 7;
    int lo = (int)(((long long)slice * n) >> 3);
    int hi = (int)(((long long)(slice + 1) * n) >> 3);
    int tid = (blockIdx.x >> 3) * blockDim.x + threadIdx.x;
    int stride = (gridDim.x >> 3) * blockDim.x;
    for (int e = tid; e < nE; e += stride) {
        int d = dst[e];
        if (d >= lo && d < hi) atomicAdd(&rp[d], 1);
    }
}

// ---------------------------------------------------------------------------
// Scan phase 1: per-chunk sums
// ---------------------------------------------------------------------------
__global__ void k_chunksum(const int* __restrict__ rp, int* __restrict__ csum, int n)
{
    __shared__ int red[4];
    int t = threadIdx.x;
    int base = blockIdx.x * SCH;
    int i = base + 2 * t;
    int s = 0;
    if (i < n)     s += rp[i];
    if (i + 1 < n) s += rp[i + 1];
#pragma unroll
    for (int m = 32; m >= 1; m >>= 1) s += __shfl_down(s, m, 64);
    if ((t & 63) == 0) red[t >> 6] = s;
    __syncthreads();
    if (t == 0) csum[blockIdx.x] = red[0] + red[1] + red[2] + red[3];
}

// ---------------------------------------------------------------------------
// Scan phase 2: exclusive scan of chunk sums (single small block)
// ---------------------------------------------------------------------------
__global__ void k_scanchunks(int* __restrict__ csum, int nchunks)
{
    __shared__ int ls[256];
    int t = threadIdx.x;
    int v = (t < nchunks) ? csum[t] : 0;
    ls[t] = v;
    __syncthreads();
#pragma unroll
    for (int off = 1; off < 256; off <<= 1) {
        int u = (t >= off) ? ls[t - off] : 0;
        __syncthreads();
        ls[t] += u;
        __syncthreads();
    }
    if (t < nchunks) csum[t] = (t == 0) ? 0 : ls[t - 1];
}

// ---------------------------------------------------------------------------
// Scan phase 3: per-chunk exclusive scan + chunk offset; writes rp (in place),
// cursor, inv_cnt. Block b owns chunk b exclusively -> in-place is safe.
// ---------------------------------------------------------------------------
__global__ void k_scanout(int* __restrict__ rp, const int* __restrict__ csum,
                          int* __restrict__ cursor, float* __restrict__ inv_cnt,
                          int n, int nE)
{
    __shared__ int ls[256];
    int t = threadIdx.x;
    int base = blockIdx.x * SCH;
    int i = base + 2 * t;
    int a0 = (i < n)     ? rp[i]     : 0;
    int a1 = (i + 1 < n) ? rp[i + 1] : 0;
    int tsum = a0 + a1;
    ls[t] = tsum;
    __syncthreads();
#pragma unroll
    for (int off = 1; off < 256; off <<= 1) {
        int u = (t >= off) ? ls[t - off] : 0;
        __syncthreads();
        ls[t] += u;
        __syncthreads();
    }
    int excl = csum[blockIdx.x] + ls[t] - tsum;
    if (i < n) {
        rp[i] = excl;
        cursor[i] = excl;
        inv_cnt[i] = 1.0f / fmaxf((float)a0, 1.0f);
    }
    if (i + 1 < n) {
        rp[i + 1] = excl + a0;
        cursor[i + 1] = excl + a0;
        inv_cnt[i + 1] = 1.0f / fmaxf((float)a1, 1.0f);
    }
    if (blockIdx.x == 0 && t == 0) rp[n] = nE;
}

// ---------------------------------------------------------------------------
// XCD-sliced scatter
// ---------------------------------------------------------------------------
__global__ void k_scatter(const int* __restrict__ src, const int* __restrict__ dst,
                          int* __restrict__ cursor, int* __restrict__ csr,
                          int n, int nE)
{
    int slice = blockIdx.x & 7;
    int lo = (int)(((long long)slice * n) >> 3);
    int hi = (int)(((long long)(slice + 1) * n) >> 3);
    int tid = (blockIdx.x >> 3) * blockDim.x + threadIdx.x;
    int stride = (gridDim.x >> 3) * blockDim.x;
    for (int e = tid; e < nE; e += stride) {
        int d = dst[e];
        if (d >= lo && d < hi) {
            int pos = atomicAdd(&cursor[d], 1);
            csr[pos] = src[e];
        }
    }
}

// ---------------------------------------------------------------------------
// Layer 1: 16 lanes per node; shfl-reduce; BN+ReLU fused; bf16 out.
// ---------------------------------------------------------------------------
__global__ void k_l1g(const int* __restrict__ rp, const int* __restrict__ csr,
                      const float* __restrict__ inv_cnt, const float* __restrict__ x,
                      const float* __restrict__ W1l, const float* __restrict__ b1l,
                      const float* __restrict__ W1r,
                      const float* __restrict__ gam, const float* __restrict__ bet,
                      const float* __restrict__ mu,  const float* __restrict__ var,
                      bf16* __restrict__ hout, int n)
{
    __shared__ float sWl[16], sb[16], sWr[16], ssc[16], sbi[16];
    int t = threadIdx.x;
    if (t < 16) {
        sWl[t] = W1l[t]; sb[t] = b1l[t]; sWr[t] = W1r[t];
        float sc = gam[t] * rsqrtf(var[t] + EPS);
        ssc[t] = sc;
        sbi[t] = bet[t] - mu[t] * sc;
    }
    __syncthreads();
    int grp = t >> 4, f = t & 15;
    int i = blockIdx.x * 16 + grp;
    if (i >= n) return;
    int r0 = rp[i], r1 = rp[i + 1];
    float s = 0.0f;
    for (int k = r0 + f; k < r1; k += 16) s += x[csr[k]];
#pragma unroll
    for (int m = 8; m >= 1; m >>= 1) s += __shfl_xor(s, m, 64);
    float mean = s * inv_cnt[i];
    float xv = x[i];
    float v = fmaf(mean, sWl[f], sb[f]);
    v = fmaf(xv, sWr[f], v);
    v = fmaxf(fmaf(v, ssc[f], sbi[f]), 0.0f);
    hout[(size_t)i * 16 + f] = __float2bfloat16(v);
}

// ---------------------------------------------------------------------------
// Layers 2,3: fused gather-mean (16 bf16 feats) + 16->16 transform + ReLU.
// ---------------------------------------------------------------------------
__global__ void k_sage16(const int* __restrict__ rp, const int* __restrict__ csr,
                         const float* __restrict__ inv_cnt, const bf16* __restrict__ h,
                         const float* __restrict__ Wl, const float* __restrict__ bl,
                         const float* __restrict__ Wr,
                         bf16* __restrict__ hout, int n)
{
    __shared__ float sWlT[256], sWrT[256], sb[16];
    __shared__ float sA[16][17], sX[16][17];
    int t = threadIdx.x;
    {
        int j = t & 15, ii = t >> 4;
        sWlT[ii * 16 + j] = Wl[j * 16 + ii];
        sWrT[ii * 16 + j] = Wr[j * 16 + ii];
    }
    if (t < 16) sb[t] = bl[t];
    int grp = t >> 4, f = t & 15;
    int i = blockIdx.x * 16 + grp;
    bool valid = i < n;
    float acc = 0.0f, ic = 0.0f, hs = 0.0f;
    if (valid) {
        int r0 = rp[i], r1 = rp[i + 1];
#pragma unroll 4
        for (int k = r0; k < r1; ++k) {
            int nb = csr[k];
            acc += __bfloat162float(h[(size_t)nb * 16 + f]);
        }
        ic = inv_cnt[i];
        hs = __bfloat162float(h[(size_t)i * 16 + f]);
    }
    sA[grp][f] = acc * ic;
    sX[grp][f] = hs;
    __syncthreads();
    if (valid) {
        float o = sb[f];
#pragma unroll
        for (int ii = 0; ii < 16; ++ii) {
            o = fmaf(sA[grp][ii], sWlT[ii * 16 + f], o);
            o = fmaf(sX[grp][ii], sWrT[ii * 16 + f], o);
        }
        hout[(size_t)i * 16 + f] = __float2bfloat16(fmaxf(o, 0.0f));
    }
}

// ---------------------------------------------------------------------------
// Layer 4 + decoder + softmax, fused with gather.
// ---------------------------------------------------------------------------
__global__ void k_fin(const int* __restrict__ rp, const int* __restrict__ csr,
                      const float* __restrict__ inv_cnt, const bf16* __restrict__ h,
                      const float* __restrict__ W4l, const float* __restrict__ b4l,
                      const float* __restrict__ W4r,
                      const float* __restrict__ Wd1, const float* __restrict__ bd1,
                      const float* __restrict__ Wd2, const float* __restrict__ bd2,
                      float* __restrict__ out, int n)
{
    __shared__ float sW4lT[512], sW4rT[512], sb4[32];
    __shared__ float sWd1T[1024], sbd1[32], sWd2[64], sbd2[2];
    __shared__ float sA[16][17], sX[16][17], sH4[16][33];
    int t = threadIdx.x;
    for (int k = t; k < 512; k += 256) {
        int j = k >> 4, ii = k & 15;
        sW4lT[ii * 32 + j] = W4l[k];
        sW4rT[ii * 32 + j] = W4r[k];
    }
    for (int k = t; k < 1024; k += 256) {
        int j = k >> 5, ii = k & 31;
        sWd1T[ii * 32 + j] = Wd1[k];
    }
    if (t < 32) { sb4[t] = b4l[t]; sbd1[t] = bd1[t]; }
    if (t < 64) sWd2[t] = Wd2[t];
    if (t < 2)  sbd2[t] = bd2[t];
    int grp = t >> 4, f = t & 15;
    int i = blockIdx.x * 16 + grp;
    bool valid = i < n;
    float acc = 0.0f, ic = 0.0f, hs = 0.0f;
    if (valid) {
        int r0 = rp[i], r1 = rp[i + 1];
#pragma unroll 4
        for (int k = r0; k < r1; ++k) acc += __bfloat162float(h[(size_t)csr[k] * 16 + f]);
        ic = inv_cnt[i];
        hs = __bfloat162float(h[(size_t)i * 16 + f]);
    }
    sA[grp][f] = acc * ic;
    sX[grp][f] = hs;
    __syncthreads();
    float h4a = sb4[f], h4b = sb4[f + 16];
#pragma unroll
    for (int ii = 0; ii < 16; ++ii) {
        float a  = sA[grp][ii];
        float xx = sX[grp][ii];
        h4a = fmaf(a,  sW4lT[ii * 32 + f],      h4a);
        h4b = fmaf(a,  sW4lT[ii * 32 + f + 16], h4b);
        h4a = fmaf(xx, sW4rT[ii * 32 + f],      h4a);
        h4b = fmaf(xx, sW4rT[ii * 32 + f + 16], h4b);
    }
    sH4[grp][f] = h4a;
    sH4[grp][f + 16] = h4b;
    __syncthreads();
    float za = sbd1[f], zb = sbd1[f + 16];
#pragma unroll
    for (int k = 0; k < 32; ++k) {
        float hv = sH4[grp][k];
        za = fmaf(hv, sWd1T[k * 32 + f],      za);
        zb = fmaf(hv, sWd1T[k * 32 + f + 16], zb);
    }
    za = fmaxf(za, 0.0f);
    zb = fmaxf(zb, 0.0f);
    float o0 = za * sWd2[f]      + zb * sWd2[f + 16];
    float o1 = za * sWd2[32 + f] + zb * sWd2[32 + f + 16];
#pragma unroll
    for (int m = 8; m >= 1; m >>= 1) {
        o0 += __shfl_xor(o0, m, 64);
        o1 += __shfl_xor(o1, m, 64);
    }
    if (valid && f == 0) {
        o0 += sbd2[0]; o1 += sbd2[1];
        float mx = fmaxf(o0, o1);
        float e0 = expf(o0 - mx), e1 = expf(o1 - mx);
        float inv = 1.0f / (e0 + e1);
        out[(size_t)2 * i + 0] = e0 * inv;
        out[(size_t)2 * i + 1] = e1 * inv;
    }
}

// ---------------------------------------------------------------------------
extern "C" void kernel_launch(void* const* d_in, const int* in_sizes, int n_in,
                              void* d_out, int out_size, void* d_ws, size_t ws_size,
                              hipStream_t stream)
{
    const float* x  = (const float*)d_in[0];
    const int*   ei = (const int*)d_in[1];
    const int    N  = in_sizes[0];
    const int    E  = in_sizes[1] / 2;
    const int* src = ei;
    const int* dst = ei + E;

    const float* W1l = (const float*)d_in[2];
    const float* b1l = (const float*)d_in[3];
    const float* W1r = (const float*)d_in[4];
    const float* gam = (const float*)d_in[5];
    const float* bet = (const float*)d_in[6];
    const float* mu  = (const float*)d_in[7];
    const float* var = (const float*)d_in[8];
    const float* W2l = (const float*)d_in[9];
    const float* b2l = (const float*)d_in[10];
    const float* W2r = (const float*)d_in[11];
    const float* W3l = (const float*)d_in[12];
    const float* b3l = (const float*)d_in[13];
    const float* W3r = (const float*)d_in[14];
    const float* W4l = (const float*)d_in[15];
    const float* b4l = (const float*)d_in[16];
    const float* W4r = (const float*)d_in[17];
    const float* Wd1 = (const float*)d_in[18];
    const float* bd1 = (const float*)d_in[19];
    const float* Wd2 = (const float*)d_in[20];
    const float* bd2 = (const float*)d_in[21];

    char*  base = (char*)d_ws;
    size_t off  = 0;
    auto alloc = [&](size_t bytes) { size_t p = off; off += (bytes + 15) & ~(size_t)15; return p; };
    float* inv_cnt = (float*)(base + alloc((size_t)N * 4));
    int*   rp      = (int*)  (base + alloc((size_t)(N + 1) * 4));
    int*   cursor  = (int*)  (base + alloc((size_t)N * 4));
    int*   csum    = (int*)  (base + alloc(256 * 4));
    int*   csr     = (int*)  (base + alloc((size_t)E * 4));
    bf16*  hA      = (bf16*) (base + alloc((size_t)N * 16 * 2));
    bf16*  hB      = (bf16*) (base + alloc((size_t)N * 16 * 2));

    int nbN16   = (N + 15) / 16;
    int nbEdge  = 8 * 256;
    int nchunks = (N + SCH - 1) / SCH;      // 196 for N=100000 (<=256 required)

    // --- build CSR ---
    hipMemsetAsync(rp, 0, (size_t)(N + 1) * sizeof(int), stream);
    k_count<<<nbEdge, 256, 0, stream>>>(dst, rp, N, E);
    k_chunksum<<<nchunks, 256, 0, stream>>>(rp, csum, N);
    k_scanchunks<<<1, 256, 0, stream>>>(csum, nchunks);
    k_scanout<<<nchunks, 256, 0, stream>>>(rp, csum, cursor, inv_cnt, N, E);
    k_scatter<<<nbEdge, 256, 0, stream>>>(src, dst, cursor, csr, N, E);

    // --- layers ---
    k_l1g<<<nbN16, 256, 0, stream>>>(rp, csr, inv_cnt, x, W1l, b1l, W1r,
                                     gam, bet, mu, var, hA, N);
    k_sage16<<<nbN16, 256, 0, stream>>>(rp, csr, inv_cnt, hA, W2l, b2l, W2r, hB, N);
    k_sage16<<<nbN16, 256, 0, stream>>>(rp, csr, inv_cnt, hB, W3l, b3l, W3r, hA, N);
    k_fin<<<nbN16, 256, 0, stream>>>(rp, csr, inv_cnt, hA, W4l, b4l, W4r,
                                     Wd1, bd1, Wd2, bd2, (float*)d_out, N);
}